// Round 6
// baseline (43.034 us; speedup 1.0000x reference)
//
#include <hip/hip_runtime.h>

// SpatialMTP1Hop:
//   err_node[n] = mean_j (H[n]·W[:,j] + b[j] - target[n][j])^2
//   owner(s) = (s<C ? s : -1) on this data (centers==arange, validated by K2
//     ballot+atomicAnd into `flag`; gather fallback for general centers).
//   per masked edge (s,d): center owner(s) accumulates (cnt, err_node[d])
//   out = mean_c errsum[c]/max(cnt[c],1)
//
// R5 accounting: K1 was ~20us = 2.4x its 8.5us HBM roofline — only 16B/lane
// in flight. R6 K1: 8 lanes/node, each lane 4 independent float4 loads (64B
// line), 8 nodes/wave, 3-level shuffle. K3 buckets edges (int4, 2-pass, 2KB
// LDS); K4 per-bucket LDS u64 fixed-point reduce (exact, deterministic).

#define CNT_SHIFT 44
#define ERR_SCALE 67108864.0f     // 2^26 fixed-point for err
#define BKT_SHIFT 8               // 256 centers per bucket
#define BKT_SIZE  256
#define CAP       8192            // slots per bucket (expected ~4080)
#define K3_BLOCKS 256
#define K3_THREADS 1024

// K1: per-node out_head MSE. 8 lanes/node: lane j owns rows [16j,16j+16),
// 4 independent float4 H loads (64B/lane), W slice via 12 float4 L1 loads,
// 3-level shuffle reduce. Also: owner sentinel + gcursor/out/flag init.
__global__ __launch_bounds__(256)
void err_node_kernel(const float* __restrict__ H,
                     const float* __restrict__ W,
                     const float* __restrict__ b,
                     const float* __restrict__ target,
                     float* __restrict__ err_node,
                     int* __restrict__ owner_of,
                     unsigned int* __restrict__ gcursor,
                     int* __restrict__ flag,
                     float* __restrict__ out,
                     int N, int NB, int out_size) {
    int gtid = blockIdx.x * blockDim.x + threadIdx.x;
    if (gtid < N) owner_of[gtid] = -1;     // sentinel (scatter comes in K2)
    if (gtid < NB) gcursor[gtid] = 0u;
    if (gtid < out_size) out[gtid] = 0.f;
    if (gtid == 0) *flag = 1;              // "centers==arange" until disproven

    int lane = threadIdx.x & 63;
    int j    = lane & 7;                   // D-slice [16j, 16j+16)
    int sub  = lane >> 3;                  // node within this wave's octet
    int node = (gtid >> 6) * 8 + sub;
    if (node >= N) return;                 // whole 8-lane group exits together

    // 4 independent float4 loads = this lane's own 64B line of the row
    const float4* h4 = reinterpret_cast<const float4*>(H + (size_t)node * 128);
    float4 h0 = h4[4 * j + 0];
    float4 h1 = h4[4 * j + 1];
    float4 h2 = h4[4 * j + 2];
    float4 h3 = h4[4 * j + 3];

    // W rows [16j,16j+16) = floats [48j,48j+48) = 12 aligned float4s (L1-hot)
    const float4* w4 = reinterpret_cast<const float4*>(W) + 12 * j;
    float wr[48];
    #pragma unroll
    for (int r = 0; r < 12; ++r) {
        float4 wv = w4[r];
        wr[4 * r + 0] = wv.x; wr[4 * r + 1] = wv.y;
        wr[4 * r + 2] = wv.z; wr[4 * r + 3] = wv.w;
    }

    float a0 = 0.f, a1 = 0.f, a2 = 0.f;
    float hx[16] = {h0.x, h0.y, h0.z, h0.w, h1.x, h1.y, h1.z, h1.w,
                    h2.x, h2.y, h2.z, h2.w, h3.x, h3.y, h3.z, h3.w};
    #pragma unroll
    for (int r = 0; r < 16; ++r) {
        a0 += hx[r] * wr[r * 3 + 0];
        a1 += hx[r] * wr[r * 3 + 1];
        a2 += hx[r] * wr[r * 3 + 2];
    }
    // reduce over j (3 levels, stays within the 8-lane group)
    #pragma unroll
    for (int m = 4; m > 0; m >>= 1) {
        a0 += __shfl_xor(a0, m, 64);
        a1 += __shfl_xor(a1, m, 64);
        a2 += __shfl_xor(a2, m, 64);
    }
    if (j == 0) {
        float e0 = a0 + b[0] - target[(size_t)node * 3 + 0];
        float e1 = a1 + b[1] - target[(size_t)node * 3 + 1];
        float e2 = a2 + b[2] - target[(size_t)node * 3 + 2];
        err_node[node] = (e0 * e0 + e1 * e1 + e2 * e2) * (1.0f / 3.0f);
    }
}

// K2: scatter center slots + validate centers==arange (ballot, rare atomics)
__global__ __launch_bounds__(256)
void owner_scatter_kernel(const int* __restrict__ centers,
                          int* __restrict__ owner_of,
                          int* __restrict__ flag, int C) {
    int i = blockIdx.x * blockDim.x + threadIdx.x;
    bool mismatch = false;
    if (i < C) {
        int c = centers[i];
        owner_of[c] = i;
        mismatch = (c != i);
    }
    unsigned long long m = __ballot(mismatch);
    if (m != 0ull && (threadIdx.x & 63) == 0) atomicAnd(flag, 0);
}

// K3: bucketize masked edges (int4 reads, two-pass recompute, 2KB LDS)
__global__ __launch_bounds__(K3_THREADS)
void bucketize_kernel(const int* __restrict__ eidx,
                      const int* __restrict__ owner_of,
                      const int* __restrict__ flag,
                      unsigned int* __restrict__ gcursor,
                      unsigned int* __restrict__ pairs,
                      int E, int C, int NB) {
    __shared__ unsigned int hist[256];
    __shared__ unsigned int base[256];
    int t = threadIdx.x;
    bool fast = (*flag != 0);                    // uniform across block
    int E4 = E >> 2;
    int chunk4 = (E4 + K3_BLOCKS - 1) / K3_BLOCKS;
    int c0 = blockIdx.x * chunk4;
    int c1 = min(E4, c0 + chunk4);
    if (t < 256) hist[t] = 0u;
    __syncthreads();

    const int4* row0 = reinterpret_cast<const int4*>(eidx);
    const int4* row1 = reinterpret_cast<const int4*>(eidx + E);

    for (int i = c0 + t; i < c1; i += K3_THREADS) {
        int4 s4 = row0[i];
        int ss[4] = {s4.x, s4.y, s4.z, s4.w};
        #pragma unroll
        for (int k = 0; k < 4; ++k) {
            int o = fast ? (ss[k] < C ? ss[k] : -1) : owner_of[ss[k]];
            if (o >= 0) atomicAdd(&hist[(unsigned)o >> BKT_SHIFT], 1u);
        }
    }
    __syncthreads();
    if (t < NB) {
        unsigned int h = hist[t];
        base[t] = h ? atomicAdd(&gcursor[t], h) : 0u;
        hist[t] = 0u;                            // reuse as local cursor
    }
    __syncthreads();
    for (int i = c0 + t; i < c1; i += K3_THREADS) {
        int4 s4 = row0[i];
        int4 d4 = row1[i];
        int ss[4] = {s4.x, s4.y, s4.z, s4.w};
        int dd[4] = {d4.x, d4.y, d4.z, d4.w};
        #pragma unroll
        for (int k = 0; k < 4; ++k) {
            int o = fast ? (ss[k] < C ? ss[k] : -1) : owner_of[ss[k]];
            if (o >= 0) {
                unsigned int bk = (unsigned)o >> BKT_SHIFT;
                unsigned int slot = base[bk] + atomicAdd(&hist[bk], 1u);
                if (slot < CAP)
                    pairs[(size_t)bk * CAP + slot] =
                        (((unsigned)o & (BKT_SIZE - 1)) << 17) | (unsigned)dd[k];
            }
        }
    }
}

// K4: per-bucket LDS u64 reduction + per-center mean + grand sum
__global__ __launch_bounds__(512)
void reduce_kernel(const unsigned int* __restrict__ pairs,
                   const unsigned int* __restrict__ gcursor,
                   const float* __restrict__ err_node,
                   float* __restrict__ out, int C, float invC) {
    __shared__ unsigned long long bins[BKT_SIZE];
    int bk = blockIdx.x, t = threadIdx.x;
    if (t < BKT_SIZE) bins[t] = 0ull;
    __syncthreads();
    unsigned int count = gcursor[bk];
    if (count > CAP) count = CAP;
    for (unsigned int i = t; i < count; i += 512) {
        unsigned int p = pairs[(size_t)bk * CAP + i];
        float err = err_node[p & 0x1FFFFu];
        atomicAdd(&bins[p >> 17],
                  (1ull << CNT_SHIFT) + (unsigned long long)(err * ERR_SCALE));
    }
    __syncthreads();
    float term = 0.f;
    if (t < BKT_SIZE) {
        int center = bk * BKT_SIZE + t;
        if (center < C) {
            unsigned long long u = bins[t];
            float cnt = (float)(u >> CNT_SHIFT);
            float es  = (float)(u & ((1ull << CNT_SHIFT) - 1)) * (1.0f / ERR_SCALE);
            term = es / fmaxf(cnt, 1.0f);
        }
    }
    #pragma unroll
    for (int m = 32; m > 0; m >>= 1) term += __shfl_down(term, m, 64);
    __shared__ float wsum[8];
    if ((t & 63) == 0) wsum[t >> 6] = term;
    __syncthreads();
    if (t == 0) {
        float s = 0.f;
        #pragma unroll
        for (int w = 0; w < 8; ++w) s += wsum[w];
        atomicAdd(out, s * invC);
    }
}

// ---- fallback path (R2-style) if workspace too small / shapes unexpected ----
__global__ void edge_atomic_kernel(const int* __restrict__ eidx,
                                   const int* __restrict__ owner_of,
                                   const float* __restrict__ err_node,
                                   unsigned long long* __restrict__ bins,
                                   int E, int C, int Rmask) {
    int e = blockIdx.x * blockDim.x + threadIdx.x;
    if (e >= E) return;
    int s = eidx[e];
    int o = owner_of[s];
    if (o >= 0) {
        int d = eidx[E + e];
        unsigned long long add = (1ull << CNT_SHIFT)
                               + (unsigned long long)(err_node[d] * ERR_SCALE);
        atomicAdd(&bins[(size_t)(threadIdx.x & Rmask) * C + o], add);
    }
}

__global__ void finalize_kernel(const unsigned long long* __restrict__ bins,
                                float* __restrict__ out, int C, int R) {
    int i = blockIdx.x * blockDim.x + threadIdx.x;
    float term = 0.f;
    if (i < C) {
        unsigned long long sum = 0ull;
        for (int r = 0; r < R; ++r) sum += bins[(size_t)r * C + i];
        float cnt = (float)(sum >> CNT_SHIFT);
        float es  = (float)(sum & ((1ull << CNT_SHIFT) - 1)) * (1.0f / ERR_SCALE);
        term = es / fmaxf(cnt, 1.0f);
    }
    #pragma unroll
    for (int m = 32; m > 0; m >>= 1) term += __shfl_down(term, m, 64);
    __shared__ float wsum[4];
    if ((threadIdx.x & 63) == 0) wsum[threadIdx.x >> 6] = term;
    __syncthreads();
    if (threadIdx.x == 0)
        atomicAdd(out, (wsum[0] + wsum[1] + wsum[2] + wsum[3]) / (float)C);
}

extern "C" void kernel_launch(void* const* d_in, const int* in_sizes, int n_in,
                              void* d_out, int out_size, void* d_ws, size_t ws_size,
                              hipStream_t stream) {
    const float* H      = (const float*)d_in[0];
    const float* W      = (const float*)d_in[1];
    const float* b      = (const float*)d_in[2];
    const float* target = (const float*)d_in[3];
    const int*   eidx   = (const int*)d_in[4];
    const int*   ctrs   = (const int*)d_in[5];

    const int DO = in_sizes[2];
    const int D  = in_sizes[1] / DO;     // 128
    const int N  = in_sizes[0] / D;      // 100000
    const int E  = in_sizes[4] / 2;      // 1600000
    const int C  = in_sizes[5];          // 50000
    const int NB = (C + BKT_SIZE - 1) >> BKT_SHIFT;   // 196

    size_t off = 0;
    auto take = [&](size_t bytes) {
        void* p = (char*)d_ws + off;
        off = (off + bytes + 255) & ~255ull;
        return p;
    };
    float* err_node = (float*)take((size_t)N * 4);
    int*   owner_of = (int*)take((size_t)N * 4);
    unsigned int* gcursor = (unsigned int*)take((size_t)NB * 4);
    int*   flag   = (int*)take(256);
    unsigned int* pairs = (unsigned int*)((char*)d_ws + off);
    size_t need = off + (size_t)NB * CAP * 4;

    // K1: err_node (8 lanes/node, 64B/lane) + sentinel/cursor/out/flag init
    {
        long long waves = (N + 7) / 8;               // 8 nodes per wave
        long long threads = waves * 64;
        int blocks = (int)((threads + 255) / 256);
        err_node_kernel<<<blocks, 256, 0, stream>>>(H, W, b, target,
                                                    err_node, owner_of, gcursor,
                                                    flag, (float*)d_out,
                                                    N, NB, out_size);
    }
    // K2: center scatter + arange validation
    owner_scatter_kernel<<<(C + 255) / 256, 256, 0, stream>>>(ctrs, owner_of,
                                                              flag, C);

    bool fits = (ws_size >= need) && (NB <= 256) && (C < (1 << 16)) &&
                (N < (1 << 17)) && ((E & 3) == 0);
    if (fits) {
        bucketize_kernel<<<K3_BLOCKS, K3_THREADS, 0, stream>>>(eidx, owner_of,
                                                               flag, gcursor,
                                                               pairs, E, C, NB);
        reduce_kernel<<<NB, 512, 0, stream>>>(pairs, gcursor, err_node,
                                              (float*)d_out, C, 1.0f / (float)C);
    } else {
        size_t rem = (ws_size > off) ? ws_size - off : 0;
        int R = (int)(rem / ((size_t)C * 8));
        if (R >= 8) R = 8; else if (R >= 4) R = 4; else if (R >= 2) R = 2; else R = 1;
        unsigned long long* bins = (unsigned long long*)((char*)d_ws + off);
        hipMemsetAsync(bins, 0, (size_t)R * C * 8, stream);
        edge_atomic_kernel<<<(E + 255) / 256, 256, 0, stream>>>(eidx, owner_of,
                                                                err_node, bins,
                                                                E, C, R - 1);
        finalize_kernel<<<(C + 255) / 256, 256, 0, stream>>>(bins, (float*)d_out, C, R);
    }
}

// Round 7
// 42.294 us; speedup vs baseline: 1.0175x; 1.0175x over previous
//
#include <hip/hip_runtime.h>

// SpatialMTP1Hop:
//   err_node[n] = mean_j (H[n]·W[:,j] + b[j] - target[n][j])^2
//   owner(s) = (s<C ? s : -1) on this data (centers==arange, validated by K2
//     ballot+atomicAnd into `flag`; gather fallback for general centers).
//   per masked edge (s,d): center owner(s) accumulates (cnt, err_node[d])
//   out = mean_c errsum[c]/max(cnt[c],1)
//
// R6 lesson: K1 is VMEM-issue/latency bound (throughput ~ bytes/VMEM-instr:
// 8B/lane=1.25TB/s, 16B/lane=2.1TB/s), and MLP must come WITHOUT register
// blowup (R6's 120-VGPR version halved occupancy and regressed). R7 K1:
// 32 lanes/node layout (W slice = 12 floats, loaded once), 4 nodes/thread =
// 4 independent float4 loads in flight, ~50 VGPR, 8 waves/SIMD.

#define CNT_SHIFT 44
#define ERR_SCALE 67108864.0f     // 2^26 fixed-point for err
#define BKT_SHIFT 8               // 256 centers per bucket
#define BKT_SIZE  256
#define CAP       8192            // slots per bucket (expected ~4080)
#define K3_BLOCKS 256
#define K3_THREADS 1024

// K1: per-node out_head MSE. Wave covers 8 consecutive nodes; thread
// (sub=lane>>5, l32=lane&31) handles element chunk [4*l32,4*l32+4) of nodes
// n0+2k+sub for k=0..3 — 4 independent float4 loads, W slice reused 4x.
// Also: owner sentinel + gcursor/out/flag init (independent stores).
__global__ __launch_bounds__(256)
void err_node_kernel(const float* __restrict__ H,
                     const float* __restrict__ W,
                     const float* __restrict__ b,
                     const float* __restrict__ target,
                     float* __restrict__ err_node,
                     int* __restrict__ owner_of,
                     unsigned int* __restrict__ gcursor,
                     int* __restrict__ flag,
                     float* __restrict__ out,
                     int N, int NB, int out_size) {
    int gtid = blockIdx.x * blockDim.x + threadIdx.x;
    if (gtid < N) owner_of[gtid] = -1;     // sentinel (scatter comes in K2)
    if (gtid < NB) gcursor[gtid] = 0u;
    if (gtid < out_size) out[gtid] = 0.f;
    if (gtid == 0) *flag = 1;              // "centers==arange" until disproven

    int lane = threadIdx.x & 63;
    int sub  = lane >> 5;                  // which of 2 rows per iteration
    int l32  = lane & 31;                  // element chunk [4*l32, 4*l32+4)
    int n0   = (gtid >> 6) * 8;            // this wave's 8-node base
    if (n0 >= N) return;

    // W rows [4*l32, 4*l32+4) x 3 cols = 12 floats, loaded once, reused 4x
    const float* wbase = W + (size_t)(4 * l32) * 3;
    float wr[12];
    #pragma unroll
    for (int r = 0; r < 12; ++r) wr[r] = wbase[r];

    // 4 independent 1KB-contiguous wave loads (nodes n0+2k+sub, k=0..3)
    float4 hv[4];
    int nd[4];
    #pragma unroll
    for (int k = 0; k < 4; ++k) {
        nd[k] = n0 + 2 * k + sub;
        if (nd[k] < N)
            hv[k] = reinterpret_cast<const float4*>(
                        H + (size_t)nd[k] * 128)[l32];
        else
            hv[k] = make_float4(0.f, 0.f, 0.f, 0.f);
    }

    #pragma unroll
    for (int k = 0; k < 4; ++k) {
        float hx[4] = {hv[k].x, hv[k].y, hv[k].z, hv[k].w};
        float a0 = 0.f, a1 = 0.f, a2 = 0.f;
        #pragma unroll
        for (int r = 0; r < 4; ++r) {
            a0 += hx[r] * wr[r * 3 + 0];
            a1 += hx[r] * wr[r * 3 + 1];
            a2 += hx[r] * wr[r * 3 + 2];
        }
        // reduce over the 32-lane half (xor masks <32 stay in-half)
        #pragma unroll
        for (int m = 16; m > 0; m >>= 1) {
            a0 += __shfl_xor(a0, m, 64);
            a1 += __shfl_xor(a1, m, 64);
            a2 += __shfl_xor(a2, m, 64);
        }
        if (l32 == 0 && nd[k] < N) {
            float e0 = a0 + b[0] - target[(size_t)nd[k] * 3 + 0];
            float e1 = a1 + b[1] - target[(size_t)nd[k] * 3 + 1];
            float e2 = a2 + b[2] - target[(size_t)nd[k] * 3 + 2];
            err_node[nd[k]] = (e0 * e0 + e1 * e1 + e2 * e2) * (1.0f / 3.0f);
        }
    }
}

// K2: scatter center slots + validate centers==arange (ballot, rare atomics)
__global__ __launch_bounds__(256)
void owner_scatter_kernel(const int* __restrict__ centers,
                          int* __restrict__ owner_of,
                          int* __restrict__ flag, int C) {
    int i = blockIdx.x * blockDim.x + threadIdx.x;
    bool mismatch = false;
    if (i < C) {
        int c = centers[i];
        owner_of[c] = i;
        mismatch = (c != i);
    }
    unsigned long long m = __ballot(mismatch);
    if (m != 0ull && (threadIdx.x & 63) == 0) atomicAnd(flag, 0);
}

// K3: bucketize masked edges (int4 reads, two-pass recompute, 2KB LDS)
__global__ __launch_bounds__(K3_THREADS)
void bucketize_kernel(const int* __restrict__ eidx,
                      const int* __restrict__ owner_of,
                      const int* __restrict__ flag,
                      unsigned int* __restrict__ gcursor,
                      unsigned int* __restrict__ pairs,
                      int E, int C, int NB) {
    __shared__ unsigned int hist[256];
    __shared__ unsigned int base[256];
    int t = threadIdx.x;
    bool fast = (*flag != 0);                    // uniform across block
    int E4 = E >> 2;
    int chunk4 = (E4 + K3_BLOCKS - 1) / K3_BLOCKS;
    int c0 = blockIdx.x * chunk4;
    int c1 = min(E4, c0 + chunk4);
    if (t < 256) hist[t] = 0u;
    __syncthreads();

    const int4* row0 = reinterpret_cast<const int4*>(eidx);
    const int4* row1 = reinterpret_cast<const int4*>(eidx + E);

    for (int i = c0 + t; i < c1; i += K3_THREADS) {
        int4 s4 = row0[i];
        int ss[4] = {s4.x, s4.y, s4.z, s4.w};
        #pragma unroll
        for (int k = 0; k < 4; ++k) {
            int o = fast ? (ss[k] < C ? ss[k] : -1) : owner_of[ss[k]];
            if (o >= 0) atomicAdd(&hist[(unsigned)o >> BKT_SHIFT], 1u);
        }
    }
    __syncthreads();
    if (t < NB) {
        unsigned int h = hist[t];
        base[t] = h ? atomicAdd(&gcursor[t], h) : 0u;
        hist[t] = 0u;                            // reuse as local cursor
    }
    __syncthreads();
    for (int i = c0 + t; i < c1; i += K3_THREADS) {
        int4 s4 = row0[i];
        int4 d4 = row1[i];
        int ss[4] = {s4.x, s4.y, s4.z, s4.w};
        int dd[4] = {d4.x, d4.y, d4.z, d4.w};
        #pragma unroll
        for (int k = 0; k < 4; ++k) {
            int o = fast ? (ss[k] < C ? ss[k] : -1) : owner_of[ss[k]];
            if (o >= 0) {
                unsigned int bk = (unsigned)o >> BKT_SHIFT;
                unsigned int slot = base[bk] + atomicAdd(&hist[bk], 1u);
                if (slot < CAP)
                    pairs[(size_t)bk * CAP + slot] =
                        (((unsigned)o & (BKT_SIZE - 1)) << 17) | (unsigned)dd[k];
            }
        }
    }
}

// K4: per-bucket LDS u64 reduction + per-center mean + grand sum
__global__ __launch_bounds__(512)
void reduce_kernel(const unsigned int* __restrict__ pairs,
                   const unsigned int* __restrict__ gcursor,
                   const float* __restrict__ err_node,
                   float* __restrict__ out, int C, float invC) {
    __shared__ unsigned long long bins[BKT_SIZE];
    int bk = blockIdx.x, t = threadIdx.x;
    if (t < BKT_SIZE) bins[t] = 0ull;
    __syncthreads();
    unsigned int count = gcursor[bk];
    if (count > CAP) count = CAP;
    for (unsigned int i = t; i < count; i += 512) {
        unsigned int p = pairs[(size_t)bk * CAP + i];
        float err = err_node[p & 0x1FFFFu];
        atomicAdd(&bins[p >> 17],
                  (1ull << CNT_SHIFT) + (unsigned long long)(err * ERR_SCALE));
    }
    __syncthreads();
    float term = 0.f;
    if (t < BKT_SIZE) {
        int center = bk * BKT_SIZE + t;
        if (center < C) {
            unsigned long long u = bins[t];
            float cnt = (float)(u >> CNT_SHIFT);
            float es  = (float)(u & ((1ull << CNT_SHIFT) - 1)) * (1.0f / ERR_SCALE);
            term = es / fmaxf(cnt, 1.0f);
        }
    }
    #pragma unroll
    for (int m = 32; m > 0; m >>= 1) term += __shfl_down(term, m, 64);
    __shared__ float wsum[8];
    if ((t & 63) == 0) wsum[t >> 6] = term;
    __syncthreads();
    if (t == 0) {
        float s = 0.f;
        #pragma unroll
        for (int w = 0; w < 8; ++w) s += wsum[w];
        atomicAdd(out, s * invC);
    }
}

// ---- fallback path (R2-style) if workspace too small / shapes unexpected ----
__global__ void edge_atomic_kernel(const int* __restrict__ eidx,
                                   const int* __restrict__ owner_of,
                                   const float* __restrict__ err_node,
                                   unsigned long long* __restrict__ bins,
                                   int E, int C, int Rmask) {
    int e = blockIdx.x * blockDim.x + threadIdx.x;
    if (e >= E) return;
    int s = eidx[e];
    int o = owner_of[s];
    if (o >= 0) {
        int d = eidx[E + e];
        unsigned long long add = (1ull << CNT_SHIFT)
                               + (unsigned long long)(err_node[d] * ERR_SCALE);
        atomicAdd(&bins[(size_t)(threadIdx.x & Rmask) * C + o], add);
    }
}

__global__ void finalize_kernel(const unsigned long long* __restrict__ bins,
                                float* __restrict__ out, int C, int R) {
    int i = blockIdx.x * blockDim.x + threadIdx.x;
    float term = 0.f;
    if (i < C) {
        unsigned long long sum = 0ull;
        for (int r = 0; r < R; ++r) sum += bins[(size_t)r * C + i];
        float cnt = (float)(sum >> CNT_SHIFT);
        float es  = (float)(sum & ((1ull << CNT_SHIFT) - 1)) * (1.0f / ERR_SCALE);
        term = es / fmaxf(cnt, 1.0f);
    }
    #pragma unroll
    for (int m = 32; m > 0; m >>= 1) term += __shfl_down(term, m, 64);
    __shared__ float wsum[4];
    if ((threadIdx.x & 63) == 0) wsum[threadIdx.x >> 6] = term;
    __syncthreads();
    if (threadIdx.x == 0)
        atomicAdd(out, (wsum[0] + wsum[1] + wsum[2] + wsum[3]) / (float)C);
}

extern "C" void kernel_launch(void* const* d_in, const int* in_sizes, int n_in,
                              void* d_out, int out_size, void* d_ws, size_t ws_size,
                              hipStream_t stream) {
    const float* H      = (const float*)d_in[0];
    const float* W      = (const float*)d_in[1];
    const float* b      = (const float*)d_in[2];
    const float* target = (const float*)d_in[3];
    const int*   eidx   = (const int*)d_in[4];
    const int*   ctrs   = (const int*)d_in[5];

    const int DO = in_sizes[2];
    const int D  = in_sizes[1] / DO;     // 128
    const int N  = in_sizes[0] / D;      // 100000
    const int E  = in_sizes[4] / 2;      // 1600000
    const int C  = in_sizes[5];          // 50000
    const int NB = (C + BKT_SIZE - 1) >> BKT_SHIFT;   // 196

    size_t off = 0;
    auto take = [&](size_t bytes) {
        void* p = (char*)d_ws + off;
        off = (off + bytes + 255) & ~255ull;
        return p;
    };
    float* err_node = (float*)take((size_t)N * 4);
    int*   owner_of = (int*)take((size_t)N * 4);
    unsigned int* gcursor = (unsigned int*)take((size_t)NB * 4);
    int*   flag   = (int*)take(256);
    unsigned int* pairs = (unsigned int*)((char*)d_ws + off);
    size_t need = off + (size_t)NB * CAP * 4;

    // K1: err_node (4 nodes/thread, 4 indep float4 loads) + inits
    {
        long long waves = (N + 7) / 8;               // 8 nodes per wave
        long long threads = waves * 64;
        int blocks = (int)((threads + 255) / 256);
        err_node_kernel<<<blocks, 256, 0, stream>>>(H, W, b, target,
                                                    err_node, owner_of, gcursor,
                                                    flag, (float*)d_out,
                                                    N, NB, out_size);
    }
    // K2: center scatter + arange validation
    owner_scatter_kernel<<<(C + 255) / 256, 256, 0, stream>>>(ctrs, owner_of,
                                                              flag, C);

    bool fits = (ws_size >= need) && (NB <= 256) && (C < (1 << 16)) &&
                (N < (1 << 17)) && ((E & 3) == 0);
    if (fits) {
        bucketize_kernel<<<K3_BLOCKS, K3_THREADS, 0, stream>>>(eidx, owner_of,
                                                               flag, gcursor,
                                                               pairs, E, C, NB);
        reduce_kernel<<<NB, 512, 0, stream>>>(pairs, gcursor, err_node,
                                              (float*)d_out, C, 1.0f / (float)C);
    } else {
        size_t rem = (ws_size > off) ? ws_size - off : 0;
        int R = (int)(rem / ((size_t)C * 8));
        if (R >= 8) R = 8; else if (R >= 4) R = 4; else if (R >= 2) R = 2; else R = 1;
        unsigned long long* bins = (unsigned long long*)((char*)d_ws + off);
        hipMemsetAsync(bins, 0, (size_t)R * C * 8, stream);
        edge_atomic_kernel<<<(E + 255) / 256, 256, 0, stream>>>(eidx, owner_of,
                                                                err_node, bins,
                                                                E, C, R - 1);
        finalize_kernel<<<(C + 255) / 256, 256, 0, stream>>>(bins, (float*)d_out, C, R);
    }
}